// Round 24
// baseline (18.170 us; speedup 1.0000x reference)
//
#include <hip/hip_runtime.h>
#include <stdint.h>

#define B_SZ    8
#define N_PTS   4096
#define C_IN    64
#define C_OUT   64
#define KNN     16
#define ROWS    (B_SZ * N_PTS)      // 32768

typedef __attribute__((ext_vector_type(8))) short v8s;   // 8 bf16 (4 VGPR)
typedef __attribute__((ext_vector_type(4))) float v4f;   // MFMA acc

__device__ inline unsigned short f2bf(float f) {         // RNE f32->bf16
    unsigned int u = __float_as_uint(f);
    return (unsigned short)((u + 0x7FFFu + ((u >> 16) & 1u)) >> 16);
}

__device__ inline v8s pack8(float4 q0, float4 q1) {
    v8s a;
    a[0] = (short)f2bf(q0.x); a[1] = (short)f2bf(q0.y);
    a[2] = (short)f2bf(q0.z); a[3] = (short)f2bf(q0.w);
    a[4] = (short)f2bf(q1.x); a[5] = (short)f2bf(q1.y);
    a[6] = (short)f2bf(q1.z); a[7] = (short)f2bf(q1.w);
    return a;
}

#define PITCH 68    // 68 % 32 == 4: col-strided frag reads are 2-way (free)

// ---------------------------------------------------------------------------
// Kernel A: nbuf projection (MFMA).  nbuf[r][o] = x[r]·W2[o]  (bf16)
// 32 rows/block, grid 1024, 4 blocks/CU.  (unchanged from r22 — proven)
// ---------------------------------------------------------------------------
__global__ __launch_bounds__(256, 4) void proj_nbuf(
    const float* __restrict__ x,
    const float* __restrict__ w,
    unsigned short* __restrict__ nbuf)
{
    __shared__ float wl2[C_OUT][PITCH];     // 17 KB: W2[col][k]

    const int t     = threadIdx.x;
    const int lane  = t & 63;
    const int wv    = t >> 6;
    const int rq    = wv & 1;                            // row half
    const int ch    = wv >> 1;                           // col half
    const int batch = blockIdx.x & 7;                    // XCD-affine
    const int chunk = blockIdx.x >> 3;                   // 0..127
    const int r0    = batch * N_PTS + chunk * 32 + rq * 16;

    const int fc   = lane & 15;
    const int koff = 8 * (lane >> 4);

    const int arow = r0 + fc;
    v8s afrag[2];
#pragma unroll
    for (int ks = 0; ks < 2; ++ks) {
        const float* xp = x + (size_t)arow * C_IN + ks * 32 + koff;
        afrag[ks] = pack8(*(const float4*)xp, *(const float4*)(xp + 4));
    }

#pragma unroll
    for (int i = 0; i < 4; ++i) {
        const int idx = i * 256 + t;        // 0..1023
        const int col = idx >> 4;
        const int q   = (idx & 15) * 4;
        *(float4*)&wl2[col][q] = *(const float4*)(w + col * 128 + 64 + q);
    }
    __syncthreads();

    v8s bfrag[2][2];
#pragma unroll
    for (int ct = 0; ct < 2; ++ct) {
        const int col = ch * 32 + ct * 16 + fc;
#pragma unroll
        for (int ks = 0; ks < 2; ++ks) {
            const float* p = &wl2[col][ks * 32 + koff];
            bfrag[ct][ks] = pack8(*(const float4*)p, *(const float4*)(p + 4));
        }
    }

    v4f acc[2];
#pragma unroll
    for (int ct = 0; ct < 2; ++ct)
        acc[ct] = (v4f){0.f, 0.f, 0.f, 0.f};

#pragma unroll
    for (int ks = 0; ks < 2; ++ks)
#pragma unroll
        for (int ct = 0; ct < 2; ++ct)
            acc[ct] = __builtin_amdgcn_mfma_f32_16x16x32_bf16(
                afrag[ks], bfrag[ct][ks], acc[ct], 0, 0, 0);

    const int crow0 = r0 + (lane >> 4) * 4;
#pragma unroll
    for (int ct = 0; ct < 2; ++ct)
#pragma unroll
        for (int reg = 0; reg < 4; ++reg)
            nbuf[(size_t)(crow0 + reg) * C_OUT + ch * 32 + ct * 16 + fc] =
                f2bf(acc[ct][reg]);
}

// ---------------------------------------------------------------------------
// Kernel B: fused cbuf(MFMA) + gather + max + relu + store.
// r22 structure with ONE change: gather+fmax loop issues IMMEDIATELY after
// the MFMA (before the cbuf barrier — gathers depend only on pidx), so the
// L2 gather latency hides under cbuf LDS writes + barrier wait. cbuf tile
// goes to a separate LDS region (smc); only 8 fmax accs live across B2.
// ---------------------------------------------------------------------------
__global__ __launch_bounds__(256, 4) void gather_fused(
    const float* __restrict__ x,
    const float* __restrict__ w,
    const float* __restrict__ bias,
    const int* __restrict__ eidx,
    const unsigned short* __restrict__ nbuf,
    float* __restrict__ out)
{
    __shared__ float wld[C_OUT][PITCH];     // 17 KB: (W1-W2)[col][k]
    __shared__ float sm [32][PITCH];        // 8.5 KB: x tile -> result tile
    __shared__ float smc[32][PITCH];        // 8.5 KB: cbuf tile (separate)

    const int t    = threadIdx.x;
    const int lane = t & 63;
    const int wv   = t >> 6;                // wave 0..3
    const int b    = blockIdx.x & 7;        // batch == XCD
    const int tn   = blockIdx.x >> 3;       // 0..127
    const int n0   = tn * 32;
    const int r0g  = b * N_PTS + n0;

    // ---- Phase-C lane mapping + direct index prefetch ----
    const int sub = lane >> 3;              // 0..7
    const int o8  = (lane & 7) * 8;         // 8 channels per lane
    const int rbl = wv * 8 + sub;           // local row
    int pidx[KNN];
    {
        const int* ep = eidx + (size_t)(r0g + rbl) * KNN;
        const int4 i0 = *(const int4*)ep;
        const int4 i1 = *(const int4*)(ep + 4);
        const int4 i2 = *(const int4*)(ep + 8);
        const int4 i3 = *(const int4*)(ep + 12);
        pidx[0]=i0.x&(N_PTS-1); pidx[1]=i0.y&(N_PTS-1); pidx[2]=i0.z&(N_PTS-1); pidx[3]=i0.w&(N_PTS-1);
        pidx[4]=i1.x&(N_PTS-1); pidx[5]=i1.y&(N_PTS-1); pidx[6]=i1.z&(N_PTS-1); pidx[7]=i1.w&(N_PTS-1);
        pidx[8]=i2.x&(N_PTS-1); pidx[9]=i2.y&(N_PTS-1); pidx[10]=i2.z&(N_PTS-1); pidx[11]=i2.w&(N_PTS-1);
        pidx[12]=i3.x&(N_PTS-1); pidx[13]=i3.y&(N_PTS-1); pidx[14]=i3.z&(N_PTS-1); pidx[15]=i3.w&(N_PTS-1);
    }

    // ---- stage (W1-W2) into wld, coalesced; subtract in flight ----
#pragma unroll
    for (int i = 0; i < 4; ++i) {
        const int idx = i * 256 + t;        // 0..1023
        const int col = idx >> 4;
        const int q   = (idx & 15) * 4;
        const float4 w1 = *(const float4*)(w + col * 128 + q);
        const float4 w2 = *(const float4*)(w + col * 128 + 64 + q);
        *(float4*)&wld[col][q] =
            make_float4(w1.x - w2.x, w1.y - w2.y, w1.z - w2.z, w1.w - w2.w);
    }

    // ---- stage 32 x-rows (8 KB) coalesced ----
    {
        const float4* xsrc = (const float4*)(x + (size_t)r0g * C_IN);
#pragma unroll
        for (int i = 0; i < 2; ++i) {
            const int idx = i * 256 + t;
            *(float4*)&sm[idx >> 4][(idx & 15) * 4] = xsrc[idx];
        }
    }
    __syncthreads();                        // B1

    // ---- Phase B: cbuf tile via MFMA ----
    const int rq   = wv & 1;
    const int ch   = wv >> 1;
    const int rl0  = rq * 16;
    const int fc   = lane & 15;
    const int koff = 8 * (lane >> 4);

    v8s bC[2][2];
#pragma unroll
    for (int ct = 0; ct < 2; ++ct) {
        const int col = ch * 32 + ct * 16 + fc;
#pragma unroll
        for (int ks = 0; ks < 2; ++ks) {
            const float* p = &wld[col][ks * 32 + koff];
            bC[ct][ks] = pack8(*(const float4*)p, *(const float4*)(p + 4));
        }
    }

    const int rl = rl0 + fc;
    v8s af[2];
#pragma unroll
    for (int ks = 0; ks < 2; ++ks) {
        const float* xp = &sm[rl][ks * 32 + koff];
        af[ks] = pack8(*(const float4*)xp, *(const float4*)(xp + 4));
    }

    v4f acc[2];
#pragma unroll
    for (int ct = 0; ct < 2; ++ct) {
        const float bv = bias[ch * 32 + ct * 16 + fc];
        acc[ct] = (v4f){bv, bv, bv, bv};
    }
#pragma unroll
    for (int ks = 0; ks < 2; ++ks)
#pragma unroll
        for (int ct = 0; ct < 2; ++ct)
            acc[ct] = __builtin_amdgcn_mfma_f32_16x16x32_bf16(
                af[ks], bC[ct][ks], acc[ct], 0, 0, 0);

    // ---- gather + fmax NOW (VMEM only; latency hides under cbuf writes) ----
    const unsigned short* nb = nbuf + (size_t)b * N_PTS * C_OUT;
    float m0 = -1e30f, m1 = -1e30f, m2 = -1e30f, m3 = -1e30f;
    float m4 = -1e30f, m5 = -1e30f, m6 = -1e30f, m7 = -1e30f;
#pragma unroll
    for (int k = 0; k < KNN; ++k) {
        const uint4 v = *(const uint4*)(nb + (size_t)pidx[k] * C_OUT + o8);
        m0 = fmaxf(m0, __uint_as_float(v.x << 16));
        m1 = fmaxf(m1, __uint_as_float(v.x & 0xffff0000u));
        m2 = fmaxf(m2, __uint_as_float(v.y << 16));
        m3 = fmaxf(m3, __uint_as_float(v.y & 0xffff0000u));
        m4 = fmaxf(m4, __uint_as_float(v.z << 16));
        m5 = fmaxf(m5, __uint_as_float(v.z & 0xffff0000u));
        m6 = fmaxf(m6, __uint_as_float(v.w << 16));
        m7 = fmaxf(m7, __uint_as_float(v.w & 0xffff0000u));
    }

    // ---- cbuf tile -> separate LDS region (no WAR with x reads needed) ----
    const int orow = rl0 + (lane >> 4) * 4;
#pragma unroll
    for (int ct = 0; ct < 2; ++ct)
#pragma unroll
        for (int reg = 0; reg < 4; ++reg)
            smc[orow + reg][ch * 32 + ct * 16 + fc] = acc[ct][reg];

    __syncthreads();                        // B2: cbuf complete (gathers retired)

    // ---- combine: cv + max, relu; result into sm ----
    const float4 cva = *(const float4*)&smc[rbl][o8];
    const float4 cvb = *(const float4*)&smc[rbl][o8 + 4];

    sm[rbl][o8 + 0] = fmaxf(cva.x + m0, 0.f);   // relu(max)==max(relu)
    sm[rbl][o8 + 1] = fmaxf(cva.y + m1, 0.f);
    sm[rbl][o8 + 2] = fmaxf(cva.z + m2, 0.f);
    sm[rbl][o8 + 3] = fmaxf(cva.w + m3, 0.f);
    sm[rbl][o8 + 4] = fmaxf(cvb.x + m4, 0.f);
    sm[rbl][o8 + 5] = fmaxf(cvb.y + m5, 0.f);
    sm[rbl][o8 + 6] = fmaxf(cvb.z + m6, 0.f);
    sm[rbl][o8 + 7] = fmaxf(cvb.w + m7, 0.f);

    __syncthreads();                        // B3

    // ---- transposed coalesced store ----
    float* ob = out + (size_t)b * C_OUT * N_PTS + n0;
    const int nn = lane & 31;
    const int oh = lane >> 5;
#pragma unroll
    for (int j = 0; j < 8; ++j) {
        const int o = wv * 16 + j * 2 + oh;
        ob[(size_t)o * N_PTS + nn] = sm[nn][o];   // 2x128B segments
    }
}

// ---------------------------------------------------------------------------
extern "C" void kernel_launch(void* const* d_in, const int* in_sizes, int n_in,
                              void* d_out, int out_size, void* d_ws, size_t ws_size,
                              hipStream_t stream)
{
    const float* x    = (const float*)d_in[0];
    const int*   eidx = (const int*)d_in[1];    // int64 in ref -> int32 here
    const float* w    = (const float*)d_in[2];  // (64, 128)
    const float* bias = (const float*)d_in[3];  // (64,)
    float*       out  = (float*)d_out;          // (8, 64, 64, 64) f32

    unsigned short* nbuf = (unsigned short*)d_ws;   // 4 MiB

    proj_nbuf<<<ROWS / 32, 256, 0, stream>>>(x, w, nbuf);
    gather_fused<<<ROWS / 32, 256, 0, stream>>>(x, w, bias, eidx, nbuf, out);
}

// Round 25
// 17.035 us; speedup vs baseline: 1.0666x; 1.0666x over previous
//
#include <hip/hip_runtime.h>
#include <stdint.h>

#define B_SZ    8
#define N_PTS   4096
#define C_IN    64
#define C_OUT   64
#define KNN     16
#define ROWS    (B_SZ * N_PTS)      // 32768

typedef __attribute__((ext_vector_type(8))) short v8s;   // 8 bf16 (4 VGPR)
typedef __attribute__((ext_vector_type(4))) float v4f;   // MFMA acc

__device__ inline unsigned short f2bf(float f) {         // RNE f32->bf16
    unsigned int u = __float_as_uint(f);
    return (unsigned short)((u + 0x7FFFu + ((u >> 16) & 1u)) >> 16);
}

__device__ inline v8s pack8(float4 q0, float4 q1) {
    v8s a;
    a[0] = (short)f2bf(q0.x); a[1] = (short)f2bf(q0.y);
    a[2] = (short)f2bf(q0.z); a[3] = (short)f2bf(q0.w);
    a[4] = (short)f2bf(q1.x); a[5] = (short)f2bf(q1.y);
    a[6] = (short)f2bf(q1.z); a[7] = (short)f2bf(q1.w);
    return a;
}

#define PITCH 68    // 68 % 32 == 4: col-strided frag reads are 2-way (free)

// ---------------------------------------------------------------------------
// Kernel A: nbuf projection (MFMA).  nbuf[r][o] = x[r]·W2[o]  (bf16)
// 32 rows/block -> grid 1024, 4 blocks/CU.
// Wave wv = (row half rq) x (col half ch).  W2 staged in LDS (coalesced).
// ---------------------------------------------------------------------------
__global__ __launch_bounds__(256, 4) void proj_nbuf(
    const float* __restrict__ x,
    const float* __restrict__ w,
    unsigned short* __restrict__ nbuf)
{
    __shared__ float wl2[C_OUT][PITCH];     // 17 KB: W2[col][k]

    const int t     = threadIdx.x;
    const int lane  = t & 63;
    const int wv    = t >> 6;
    const int rq    = wv & 1;                            // row half
    const int ch    = wv >> 1;                           // col half
    const int batch = blockIdx.x & 7;                    // XCD-affine
    const int chunk = blockIdx.x >> 3;                   // 0..127
    const int r0    = batch * N_PTS + chunk * 32 + rq * 16;

    const int fc   = lane & 15;
    const int koff = 8 * (lane >> 4);

    // afrag: direct from x (issues before the barrier)
    const int arow = r0 + fc;
    v8s afrag[2];
#pragma unroll
    for (int ks = 0; ks < 2; ++ks) {
        const float* xp = x + (size_t)arow * C_IN + ks * 32 + koff;
        afrag[ks] = pack8(*(const float4*)xp, *(const float4*)(xp + 4));
    }

    // stage W2 (coalesced)
#pragma unroll
    for (int i = 0; i < 4; ++i) {
        const int idx = i * 256 + t;        // 0..1023
        const int col = idx >> 4;
        const int q   = (idx & 15) * 4;
        *(float4*)&wl2[col][q] = *(const float4*)(w + col * 128 + 64 + q);
    }
    __syncthreads();

    v8s bfrag[2][2];
#pragma unroll
    for (int ct = 0; ct < 2; ++ct) {
        const int col = ch * 32 + ct * 16 + fc;
#pragma unroll
        for (int ks = 0; ks < 2; ++ks) {
            const float* p = &wl2[col][ks * 32 + koff];
            bfrag[ct][ks] = pack8(*(const float4*)p, *(const float4*)(p + 4));
        }
    }

    v4f acc[2];
#pragma unroll
    for (int ct = 0; ct < 2; ++ct)
        acc[ct] = (v4f){0.f, 0.f, 0.f, 0.f};

#pragma unroll
    for (int ks = 0; ks < 2; ++ks)
#pragma unroll
        for (int ct = 0; ct < 2; ++ct)
            acc[ct] = __builtin_amdgcn_mfma_f32_16x16x32_bf16(
                afrag[ks], bfrag[ct][ks], acc[ct], 0, 0, 0);

    const int crow0 = r0 + (lane >> 4) * 4;
#pragma unroll
    for (int ct = 0; ct < 2; ++ct)
#pragma unroll
        for (int reg = 0; reg < 4; ++reg)
            nbuf[(size_t)(crow0 + reg) * C_OUT + ch * 32 + ct * 16 + fc] =
                f2bf(acc[ct][reg]);
}

// ---------------------------------------------------------------------------
// Kernel B: fused cbuf(MFMA, LDS-only) + gather + max + relu + store.
// Phase-C indices loaded per-lane direct from eidx (4x dwordx4 at kernel
// top; 8 lanes share each 64B line).  uint4 gathers: 8 lanes/row,
// 8 rows/instr, 16 gather instrs/wave.
// ---------------------------------------------------------------------------
__global__ __launch_bounds__(256, 4) void gather_fused(
    const float* __restrict__ x,
    const float* __restrict__ w,
    const float* __restrict__ bias,
    const int* __restrict__ eidx,
    const unsigned short* __restrict__ nbuf,
    float* __restrict__ out)
{
    __shared__ float wld[C_OUT][PITCH];     // 17 KB: (W1-W2)[col][k]
    __shared__ float sm[32][PITCH];         // 8.5 KB: x -> cbuf -> result

    const int t    = threadIdx.x;
    const int lane = t & 63;
    const int wv   = t >> 6;                // wave 0..3
    const int b    = blockIdx.x & 7;        // batch == XCD
    const int tn   = blockIdx.x >> 3;       // 0..127
    const int n0   = tn * 32;
    const int r0g  = b * N_PTS + n0;

    // ---- Phase-C row for this lane + direct index prefetch ----
    const int sub  = lane >> 3;             // 0..7
    const int o8   = (lane & 7) * 8;        // 8 channels per lane
    const int rbl  = wv * 8 + sub;          // local row
    int pidx[KNN];
    {
        const int* ep = eidx + (size_t)(r0g + rbl) * KNN;
        const int4 i0 = *(const int4*)ep;
        const int4 i1 = *(const int4*)(ep + 4);
        const int4 i2 = *(const int4*)(ep + 8);
        const int4 i3 = *(const int4*)(ep + 12);
        pidx[0]=i0.x&(N_PTS-1); pidx[1]=i0.y&(N_PTS-1); pidx[2]=i0.z&(N_PTS-1); pidx[3]=i0.w&(N_PTS-1);
        pidx[4]=i1.x&(N_PTS-1); pidx[5]=i1.y&(N_PTS-1); pidx[6]=i1.z&(N_PTS-1); pidx[7]=i1.w&(N_PTS-1);
        pidx[8]=i2.x&(N_PTS-1); pidx[9]=i2.y&(N_PTS-1); pidx[10]=i2.z&(N_PTS-1); pidx[11]=i2.w&(N_PTS-1);
        pidx[12]=i3.x&(N_PTS-1); pidx[13]=i3.y&(N_PTS-1); pidx[14]=i3.z&(N_PTS-1); pidx[15]=i3.w&(N_PTS-1);
    }

    // ---- stage (W1-W2) into wld, coalesced; subtract in flight ----
#pragma unroll
    for (int i = 0; i < 4; ++i) {
        const int idx = i * 256 + t;        // 0..1023
        const int col = idx >> 4;
        const int q   = (idx & 15) * 4;
        const float4 w1 = *(const float4*)(w + col * 128 + q);
        const float4 w2 = *(const float4*)(w + col * 128 + 64 + q);
        *(float4*)&wld[col][q] =
            make_float4(w1.x - w2.x, w1.y - w2.y, w1.z - w2.z, w1.w - w2.w);
    }

    // ---- stage 32 x-rows (8 KB) coalesced (disjoint LDS region) ----
    {
        const float4* xsrc = (const float4*)(x + (size_t)r0g * C_IN);
#pragma unroll
        for (int i = 0; i < 2; ++i) {
            const int idx = i * 256 + t;
            *(float4*)&sm[idx >> 4][(idx & 15) * 4] = xsrc[idx];
        }
    }
    __syncthreads();

    // ---- Phase B: cbuf tile via MFMA ----
    const int rq   = wv & 1;                // rows rq*16..+15
    const int ch   = wv >> 1;               // cols ch*32..+31
    const int rl0  = rq * 16;
    const int fc   = lane & 15;
    const int koff = 8 * (lane >> 4);

    v8s bC[2][2];
#pragma unroll
    for (int ct = 0; ct < 2; ++ct) {
        const int col = ch * 32 + ct * 16 + fc;
#pragma unroll
        for (int ks = 0; ks < 2; ++ks) {
            const float* p = &wld[col][ks * 32 + koff];
            bC[ct][ks] = pack8(*(const float4*)p, *(const float4*)(p + 4));
        }
    }

    const int rl = rl0 + fc;
    v8s af[2];
#pragma unroll
    for (int ks = 0; ks < 2; ++ks) {
        const float* xp = &sm[rl][ks * 32 + koff];
        af[ks] = pack8(*(const float4*)xp, *(const float4*)(xp + 4));
    }

    v4f acc[2];
#pragma unroll
    for (int ct = 0; ct < 2; ++ct) {
        const float bv = bias[ch * 32 + ct * 16 + fc];
        acc[ct] = (v4f){bv, bv, bv, bv};
    }
#pragma unroll
    for (int ks = 0; ks < 2; ++ks)
#pragma unroll
        for (int ct = 0; ct < 2; ++ct)
            acc[ct] = __builtin_amdgcn_mfma_f32_16x16x32_bf16(
                af[ks], bC[ct][ks], acc[ct], 0, 0, 0);

    __syncthreads();                        // all af reads from sm done

    const int orow = rl0 + (lane >> 4) * 4;
#pragma unroll
    for (int ct = 0; ct < 2; ++ct)
#pragma unroll
        for (int reg = 0; reg < 4; ++reg)
            sm[orow + reg][ch * 32 + ct * 16 + fc] = acc[ct][reg];

    __syncthreads();                        // cbuf tile complete

    // ---- Phase C: gather + max + relu, uint4 (lane owns row rbl, o8..+7) ----
    const unsigned short* nb = nbuf + (size_t)b * N_PTS * C_OUT;

    const float4 cva = *(const float4*)&sm[rbl][o8];
    const float4 cvb = *(const float4*)&sm[rbl][o8 + 4];

    float m0 = -1e30f, m1 = -1e30f, m2 = -1e30f, m3 = -1e30f;
    float m4 = -1e30f, m5 = -1e30f, m6 = -1e30f, m7 = -1e30f;
#pragma unroll
    for (int k = 0; k < KNN; ++k) {
        const uint4 v = *(const uint4*)(nb + (size_t)pidx[k] * C_OUT + o8);
        m0 = fmaxf(m0, __uint_as_float(v.x << 16));
        m1 = fmaxf(m1, __uint_as_float(v.x & 0xffff0000u));
        m2 = fmaxf(m2, __uint_as_float(v.y << 16));
        m3 = fmaxf(m3, __uint_as_float(v.y & 0xffff0000u));
        m4 = fmaxf(m4, __uint_as_float(v.z << 16));
        m5 = fmaxf(m5, __uint_as_float(v.z & 0xffff0000u));
        m6 = fmaxf(m6, __uint_as_float(v.w << 16));
        m7 = fmaxf(m7, __uint_as_float(v.w & 0xffff0000u));
    }

    sm[rbl][o8 + 0] = fmaxf(cva.x + m0, 0.f);   // relu(max)==max(relu)
    sm[rbl][o8 + 1] = fmaxf(cva.y + m1, 0.f);
    sm[rbl][o8 + 2] = fmaxf(cva.z + m2, 0.f);
    sm[rbl][o8 + 3] = fmaxf(cva.w + m3, 0.f);
    sm[rbl][o8 + 4] = fmaxf(cvb.x + m4, 0.f);
    sm[rbl][o8 + 5] = fmaxf(cvb.y + m5, 0.f);
    sm[rbl][o8 + 6] = fmaxf(cvb.z + m6, 0.f);
    sm[rbl][o8 + 7] = fmaxf(cvb.w + m7, 0.f);

    __syncthreads();

    // ---- transposed coalesced store ----
    float* ob = out + (size_t)b * C_OUT * N_PTS + n0;
    const int nn = lane & 31;
    const int oh = lane >> 5;
#pragma unroll
    for (int j = 0; j < 8; ++j) {
        const int o = wv * 16 + j * 2 + oh;
        ob[(size_t)o * N_PTS + nn] = sm[nn][o];   // 2x128B segments
    }
}

// ---------------------------------------------------------------------------
extern "C" void kernel_launch(void* const* d_in, const int* in_sizes, int n_in,
                              void* d_out, int out_size, void* d_ws, size_t ws_size,
                              hipStream_t stream)
{
    const float* x    = (const float*)d_in[0];
    const int*   eidx = (const int*)d_in[1];    // int64 in ref -> int32 here
    const float* w    = (const float*)d_in[2];  // (64, 128)
    const float* bias = (const float*)d_in[3];  // (64,)
    float*       out  = (float*)d_out;          // (8, 64, 64, 64) f32

    unsigned short* nbuf = (unsigned short*)d_ws;   // 4 MiB

    proj_nbuf<<<ROWS / 32, 256, 0, stream>>>(x, w, nbuf);
    gather_fused<<<ROWS / 32, 256, 0, stream>>>(x, w, bias, eidx, nbuf, out);
}